// Round 9
// baseline (6460.710 us; speedup 1.0000x reference)
//
#include <hip/hip_runtime.h>
#include <hip/hip_fp16.h>

typedef unsigned int u32;
typedef _Float16 h2v __attribute__((ext_vector_type(2)));
typedef _Float16 half8 __attribute__((ext_vector_type(8)));
typedef float f32x4 __attribute__((ext_vector_type(4)));

#define B_ 64
#define T_ 1024
#define H_ 512
#define I_ 512

__device__ __forceinline__ float dot2f(u32 w, u32 h, float acc) {
#if __has_builtin(__builtin_amdgcn_fdot2)
    return __builtin_amdgcn_fdot2(__builtin_bit_cast(h2v, w),
                                  __builtin_bit_cast(h2v, h), acc, false);
#else
    __half2 a = __builtin_bit_cast(__half2, w);
    __half2 b = __builtin_bit_cast(__half2, h);
    return acc + __low2float(a) * __low2float(b) + __high2float(a) * __high2float(b);
#endif
}

__device__ __forceinline__ u32 pkf16(float a, float b) {
    __half2 h = __floats2half2_rn(a, b);
    return __builtin_bit_cast(u32, h);
}

__device__ __forceinline__ f32x4 mfma16(uint4 a, uint4 b, f32x4 c) {
    return __builtin_amdgcn_mfma_f32_16x16x32_f16(
        __builtin_bit_cast(half8, a), __builtin_bit_cast(half8, b), c, 0, 0, 0);
}

__device__ __forceinline__ float tanh_f(float x) {
    float e = __expf(-2.f * fabsf(x));
    return __builtin_copysignf((1.f - e) / (1.f + e), x);
}

// ---------------- W_hh repack into MFMA A-fragments ----------------
// Wave w owns rows [w*128, w*128+128): 8 row-tiles (rt) x 16 k-tiles (kt).
// Frag(w,rt,kt), lane l, u32 q: A[row][k] with row = w*128+rt*16+(l&15),
// k = kt*32+(l>>4)*8+2q (+1 in hi half). kt 0..9 -> wregb (register-resident,
// 80 frags = 320 regs/lane); kt 10..15 -> wstrb (streamed from L2 each step).
__global__ void prep_w(const float* __restrict__ Whh, u32* __restrict__ wregb,
                       u32* __restrict__ wstrb) {
    const int tid = threadIdx.x;
    const int lane = tid >> 2, q = tid & 3;
    const int bid = blockIdx.x;
    int w, kt, rt; u32* dst;
    if (bid < 320) {            // REG frags: bid = w*80 + kt*8 + rt (kt 0..9)
        w = bid / 80; int fi = bid % 80; kt = fi >> 3; rt = fi & 7;
        dst = wregb + bid * 256;
    } else {                    // STR frags: s = w*48 + (kt-10)*8 + rt
        int s = bid - 320; w = s / 48; int r48 = s % 48;
        kt = 10 + (r48 >> 3); rt = r48 & 7;
        dst = wstrb + s * 256;
    }
    const int row = w * 128 + rt * 16 + (lane & 15);
    const int k0 = kt * 32 + (lane >> 4) * 8 + 2 * q;
    dst[tid] = pkf16(Whh[row * H_ + k0], Whh[row * H_ + k0 + 1]);
}

// ---------------- Phase 1: Xp = X @ W_ih^T + (b_ih + b_hh) (R4-proven) -------
#define BM 128
#define BN 64

__launch_bounds__(256, 3)
__global__ void gemm_xp(const float* __restrict__ X, const float* __restrict__ Wih,
                        const float* __restrict__ bih, const float* __restrict__ bhh,
                        float* __restrict__ out) {
    __shared__ u32 Xs[16][BM + 4];
    __shared__ u32 Ws[16][BN + 4];
    const int t = threadIdx.x;
    const int bn = blockIdx.x & 7;
    const int bm = blockIdx.x >> 3;
    const int m0 = bm * BM, n0 = bn * BN;
    const int tm = t & 15, tn = t >> 4;
    float acc[8][4];
#pragma unroll
    for (int i = 0; i < 8; i++)
#pragma unroll
        for (int j = 0; j < 4; j++) acc[i][j] = 0.f;
    const int kc = t & 7, rr = t >> 3;
    const int key = ((tm >> 2) & 1) << 2;
    for (int kt = 0; kt < 16; kt++) {
        const int k0 = kt * 32;
#pragma unroll
        for (int it = 0; it < 4; it++) {
            const int m = it * 32 + rr;
            float4 v = *(const float4*)&X[(size_t)(m0 + m) * I_ + k0 + kc * 4];
            const int mp = m ^ (((m >> 5) & 1) << 2);
            Xs[kc * 2 + 0][mp] = pkf16(v.x, v.y);
            Xs[kc * 2 + 1][mp] = pkf16(v.z, v.w);
        }
#pragma unroll
        for (int it = 0; it < 2; it++) {
            const int n = it * 32 + rr;
            float4 v = *(const float4*)&Wih[(size_t)(n0 + n) * I_ + k0 + kc * 4];
            Ws[kc * 2 + 0][n] = pkf16(v.x, v.y);
            Ws[kc * 2 + 1][n] = pkf16(v.z, v.w);
        }
        __syncthreads();
#pragma unroll
        for (int k2 = 0; k2 < 16; k2++) {
            uint4 a0 = *(const uint4*)&Xs[k2][(tm * 8) ^ key];
            uint4 a1 = *(const uint4*)&Xs[k2][(tm * 8 + 4) ^ key];
            uint4 bv = *(const uint4*)&Ws[k2][tn * 4];
            u32 aa[8] = {a0.x, a0.y, a0.z, a0.w, a1.x, a1.y, a1.z, a1.w};
            u32 bb[4] = {bv.x, bv.y, bv.z, bv.w};
#pragma unroll
            for (int mi = 0; mi < 8; mi++)
#pragma unroll
                for (int ni = 0; ni < 4; ni++)
                    acc[mi][ni] = dot2f(aa[mi], bb[ni], acc[mi][ni]);
        }
        __syncthreads();
    }
    float4 b1 = *(const float4*)&bih[n0 + tn * 4];
    float4 b2 = *(const float4*)&bhh[n0 + tn * 4];
    float4 bs = {b1.x + b2.x, b1.y + b2.y, b1.z + b2.z, b1.w + b2.w};
#pragma unroll
    for (int mi = 0; mi < 8; mi++) {
        const int row = m0 + tm * 8 + mi;
        float4 st = {acc[mi][0] + bs.x, acc[mi][1] + bs.y,
                     acc[mi][2] + bs.z, acc[mi][3] + bs.w};
        *(float4*)&out[(size_t)row * H_ + n0 + tn * 4] = st;
    }
}

// ---------------- Phase 2: MFMA scan ----------------
// 256 thr = 4 waves, 1 wave/SIMD (~480 unified regs). Per wave per step:
// 128 x mfma_f32_16x16x32_f16 (8 acc chains over rt, accumulate over kt).
// B = h broadcast to all 16 cols -> every lane holds valid GEMV rows.
// kt 0..9 A-frags register-resident; kt 10..15 streamed from L2 (h-independent,
// issued >=3 kt ahead of use). Tail: col-group g=lane&15 handles row-tile g&7:
// 4 tanh/lane, no reduce. h ping-pong in 2KB LDS, raw barrier (no vmcnt drain).

#define LDSTR(KT)                                                               \
    uint4 sA##KT##0 = sb[((KT - 10) * 8 + 0) * 64],                             \
          sA##KT##1 = sb[((KT - 10) * 8 + 1) * 64],                             \
          sA##KT##2 = sb[((KT - 10) * 8 + 2) * 64],                             \
          sA##KT##3 = sb[((KT - 10) * 8 + 3) * 64],                             \
          sA##KT##4 = sb[((KT - 10) * 8 + 4) * 64],                             \
          sA##KT##5 = sb[((KT - 10) * 8 + 5) * 64],                             \
          sA##KT##6 = sb[((KT - 10) * 8 + 6) * 64],                             \
          sA##KT##7 = sb[((KT - 10) * 8 + 7) * 64];

#define MF_STR(KT) {                                                            \
    uint4 bf = *(const uint4*)&hh[rbuf + KT * 16 + hi4];                        \
    a0 = mfma16(sA##KT##0, bf, a0); a1 = mfma16(sA##KT##1, bf, a1);             \
    a2 = mfma16(sA##KT##2, bf, a2); a3 = mfma16(sA##KT##3, bf, a3);             \
    a4 = mfma16(sA##KT##4, bf, a4); a5 = mfma16(sA##KT##5, bf, a5);             \
    a6 = mfma16(sA##KT##6, bf, a6); a7 = mfma16(sA##KT##7, bf, a7); }

#define MF_REG(KT) {                                                            \
    uint4 bf = *(const uint4*)&hh[rbuf + KT * 16 + hi4];                        \
    a0 = mfma16(wf[KT * 8 + 0], bf, a0); a1 = mfma16(wf[KT * 8 + 1], bf, a1);   \
    a2 = mfma16(wf[KT * 8 + 2], bf, a2); a3 = mfma16(wf[KT * 8 + 3], bf, a3);   \
    a4 = mfma16(wf[KT * 8 + 4], bf, a4); a5 = mfma16(wf[KT * 8 + 5], bf, a5);   \
    a6 = mfma16(wf[KT * 8 + 6], bf, a6); a7 = mfma16(wf[KT * 8 + 7], bf, a7); }

__launch_bounds__(256)
__attribute__((amdgpu_waves_per_eu(1, 1)))
__global__ void rnn_scan(const u32* __restrict__ wregb, const u32* __restrict__ wstrb,
                         float* __restrict__ out) {
    __shared__ __align__(16) u32 hh[512];      // 2 x 256 u32 = 2 x 512 fp16
    const int tid = threadIdx.x;
    const int w = tid >> 6, lane = tid & 63;
    const int g16 = lane & 15, hi = lane >> 4;
    const int hi4 = hi * 4, gg = g16 & 7;
    const int orow = w * 128 + gg * 16 + hi4;  // this lane's 4 output rows
    const int hslot = w * 64 + gg * 8 + hi * 2;

    uint4 wf[80];                              // kt 0..9 A-frags (320 regs)
    const uint4* wr4 = (const uint4*)wregb;
#pragma unroll
    for (int fi = 0; fi < 80; fi++) wf[fi] = wr4[(w * 80 + fi) * 64 + lane];

    hh[tid] = 0u; hh[tid + 256] = 0u;          // h0 = 0 (both buffers)
    __syncthreads();

    float* outb = out + (size_t)blockIdx.x * (T_ * H_);
    int so = (w * 48) * 64 + lane;             // stream base (made opaque per step)
    const uint4* ws4 = (const uint4*)wstrb;

#pragma unroll 1
    for (int t = 0; t < T_; t++) {
        asm volatile("" : "+v"(so));           // defeat LICM of stream loads
        const uint4* sb = ws4 + so;
        const int rbuf = (t & 1) << 8;         // read-buffer base (dwords)
        LDSTR(10) LDSTR(11) LDSTR(12)          // stream prefetch, 3 kt deep
        float4 xp = *(const float4*)&outb[(size_t)t * H_ + orow];
        f32x4 a0 = {0.f, 0.f, 0.f, 0.f}, a1 = {0.f, 0.f, 0.f, 0.f};
        f32x4 a2 = {0.f, 0.f, 0.f, 0.f}, a3 = {0.f, 0.f, 0.f, 0.f};
        f32x4 a4 = {0.f, 0.f, 0.f, 0.f}, a5 = {0.f, 0.f, 0.f, 0.f};
        f32x4 a6 = {0.f, 0.f, 0.f, 0.f}, a7 = {0.f, 0.f, 0.f, 0.f};
        MF_REG(0) MF_REG(1) MF_REG(2)
        MF_STR(10) LDSTR(13)
        MF_REG(3)
        MF_STR(11) LDSTR(14)
        MF_REG(4)
        MF_STR(12) LDSTR(15)
        MF_REG(5)
        MF_STR(13)
        MF_REG(6)
        MF_STR(14)
        MF_REG(7)
        MF_STR(15)
        MF_REG(8) MF_REG(9)
        // ---- tail: select this lane's row-tile (gg) and finish 4 rows
        f32x4 x0 = (gg & 1) ? a1 : a0;
        f32x4 x1 = (gg & 1) ? a3 : a2;
        f32x4 x2 = (gg & 1) ? a5 : a4;
        f32x4 x3 = (gg & 1) ? a7 : a6;
        f32x4 y0 = (gg & 2) ? x1 : x0;
        f32x4 y1 = (gg & 2) ? x3 : x2;
        f32x4 z  = (gg & 4) ? y1 : y0;
        const float t0 = tanh_f(xp.x + z[0]);
        const float t1 = tanh_f(xp.y + z[1]);
        const float t2 = tanh_f(xp.z + z[2]);
        const float t3 = tanh_f(xp.w + z[3]);
        if (g16 < 8) {
            float4 st = {t0, t1, t2, t3};
            *(float4*)&outb[(size_t)t * H_ + orow] = st;   // h_t overwrites Xp
            uint2 ph = {pkf16(t0, t1), pkf16(t2, t3)};
            *(uint2*)&hh[(rbuf ^ 256) + hslot] = ph;       // h -> other buffer
        }
        asm volatile("s_waitcnt lgkmcnt(0)" ::: "memory");
        __builtin_amdgcn_sched_barrier(0);
        __builtin_amdgcn_s_barrier();          // raw: stream prefetches fly on
        __builtin_amdgcn_sched_barrier(0);
    }
}

extern "C" void kernel_launch(void* const* d_in, const int* in_sizes, int n_in,
                              void* d_out, int out_size, void* d_ws, size_t ws_size,
                              hipStream_t stream) {
    const float* X    = (const float*)d_in[0];
    const float* Wih  = (const float*)d_in[1];
    const float* Whh  = (const float*)d_in[2];
    const float* bih  = (const float*)d_in[3];
    const float* bhh  = (const float*)d_in[4];
    float* out = (float*)d_out;
    // d_ws: wregb 81920 u32 (320KB) | wstrb 49152 u32 (192KB) = 512KB
    u32* wregb = (u32*)d_ws;
    u32* wstrb = wregb + 81920;

    prep_w<<<dim3(512), dim3(256), 0, stream>>>(Whh, wregb, wstrb);
    gemm_xp<<<dim3((65536 / BM) * (H_ / BN)), dim3(256), 0, stream>>>(X, Wih, bih, bhh, out);
    rnn_scan<<<dim3(B_), dim3(256), 0, stream>>>(wregb, wstrb, out);
}

// Round 10
// 1925.390 us; speedup vs baseline: 3.3555x; 3.3555x over previous
//
#include <hip/hip_runtime.h>
#include <hip/hip_fp16.h>

typedef unsigned int u32;
typedef _Float16 h2v __attribute__((ext_vector_type(2)));
typedef _Float16 half8 __attribute__((ext_vector_type(8)));
typedef float f32x4 __attribute__((ext_vector_type(4)));

#define B_ 64
#define T_ 1024
#define H_ 512
#define I_ 512

__device__ __forceinline__ float dot2f(u32 w, u32 h, float acc) {
#if __has_builtin(__builtin_amdgcn_fdot2)
    return __builtin_amdgcn_fdot2(__builtin_bit_cast(h2v, w),
                                  __builtin_bit_cast(h2v, h), acc, false);
#else
    __half2 a = __builtin_bit_cast(__half2, w);
    __half2 b = __builtin_bit_cast(__half2, h);
    return acc + __low2float(a) * __low2float(b) + __high2float(a) * __high2float(b);
#endif
}

__device__ __forceinline__ u32 pkf16(float a, float b) {
    __half2 h = __floats2half2_rn(a, b);
    return __builtin_bit_cast(u32, h);
}

__device__ __forceinline__ f32x4 mfma16(uint4 a, uint4 b, f32x4 c) {
    return __builtin_amdgcn_mfma_f32_16x16x32_f16(
        __builtin_bit_cast(half8, a), __builtin_bit_cast(half8, b), c, 0, 0, 0);
}

__device__ __forceinline__ float tanh_f(float x) {
    float e = __expf(-2.f * fabsf(x));
    return __builtin_copysignf((1.f - e) / (1.f + e), x);
}

// ---------------- W_hh repack into MFMA A-fragments ----------------
// 8 waves; wave w owns rows [w*64, w*64+64): 4 row-tiles (rt) x 16 k-tiles (kt).
// Frag(w,rt,kt), lane l, u32 q: A[row][k], row = w*64+rt*16+(l&15),
// k = kt*32+(l>>4)*8+2q (+1 hi half).  kt 0..11 -> wregb (reg-resident,
// 48 uint4 = 192 u32/lane); kt 12..15 -> wldsg (copied to 128KB LDS, re-read
// each step).  Layout verified on HW by R9's PASS (same mapping).
__global__ void prep_w(const float* __restrict__ Whh, u32* __restrict__ wregb,
                       u32* __restrict__ wldsg) {
    const int tid = threadIdx.x;
    const int lane = tid >> 2, q = tid & 3;
    const int bid = blockIdx.x;
    int w, kt, rt; u32* dst;
    if (bid < 384) {            // reg frags: bid = w*48 + kt*4 + rt (kt 0..11)
        w = bid / 48; int fi = bid % 48; kt = fi >> 2; rt = fi & 3;
        dst = wregb + bid * 256;
    } else {                    // LDS-image frags: s = w*16 + (kt-12)*4 + rt
        int s = bid - 384; w = s / 16; int r16 = s % 16;
        kt = 12 + (r16 >> 2); rt = r16 & 3;
        dst = wldsg + s * 256;
    }
    const int row = w * 64 + rt * 16 + (lane & 15);
    const int k0 = kt * 32 + (lane >> 4) * 8 + 2 * q;
    dst[tid] = pkf16(Whh[row * H_ + k0], Whh[row * H_ + k0 + 1]);
}

// ---------------- Phase 1: Xp = X @ W_ih^T + (b_ih + b_hh) (R4-proven) -------
#define BM 128
#define BN 64

__launch_bounds__(256, 3)
__global__ void gemm_xp(const float* __restrict__ X, const float* __restrict__ Wih,
                        const float* __restrict__ bih, const float* __restrict__ bhh,
                        float* __restrict__ out) {
    __shared__ u32 Xs[16][BM + 4];
    __shared__ u32 Ws[16][BN + 4];
    const int t = threadIdx.x;
    const int bn = blockIdx.x & 7;
    const int bm = blockIdx.x >> 3;
    const int m0 = bm * BM, n0 = bn * BN;
    const int tm = t & 15, tn = t >> 4;
    float acc[8][4];
#pragma unroll
    for (int i = 0; i < 8; i++)
#pragma unroll
        for (int j = 0; j < 4; j++) acc[i][j] = 0.f;
    const int kc = t & 7, rr = t >> 3;
    const int key = ((tm >> 2) & 1) << 2;
    for (int kt = 0; kt < 16; kt++) {
        const int k0 = kt * 32;
#pragma unroll
        for (int it = 0; it < 4; it++) {
            const int m = it * 32 + rr;
            float4 v = *(const float4*)&X[(size_t)(m0 + m) * I_ + k0 + kc * 4];
            const int mp = m ^ (((m >> 5) & 1) << 2);
            Xs[kc * 2 + 0][mp] = pkf16(v.x, v.y);
            Xs[kc * 2 + 1][mp] = pkf16(v.z, v.w);
        }
#pragma unroll
        for (int it = 0; it < 2; it++) {
            const int n = it * 32 + rr;
            float4 v = *(const float4*)&Wih[(size_t)(n0 + n) * I_ + k0 + kc * 4];
            Ws[kc * 2 + 0][n] = pkf16(v.x, v.y);
            Ws[kc * 2 + 1][n] = pkf16(v.z, v.w);
        }
        __syncthreads();
#pragma unroll
        for (int k2 = 0; k2 < 16; k2++) {
            uint4 a0 = *(const uint4*)&Xs[k2][(tm * 8) ^ key];
            uint4 a1 = *(const uint4*)&Xs[k2][(tm * 8 + 4) ^ key];
            uint4 bv = *(const uint4*)&Ws[k2][tn * 4];
            u32 aa[8] = {a0.x, a0.y, a0.z, a0.w, a1.x, a1.y, a1.z, a1.w};
            u32 bb[4] = {bv.x, bv.y, bv.z, bv.w};
#pragma unroll
            for (int mi = 0; mi < 8; mi++)
#pragma unroll
                for (int ni = 0; ni < 4; ni++)
                    acc[mi][ni] = dot2f(aa[mi], bb[ni], acc[mi][ni]);
        }
        __syncthreads();
    }
    float4 b1 = *(const float4*)&bih[n0 + tn * 4];
    float4 b2 = *(const float4*)&bhh[n0 + tn * 4];
    float4 bs = {b1.x + b2.x, b1.y + b2.y, b1.z + b2.z, b1.w + b2.w};
#pragma unroll
    for (int mi = 0; mi < 8; mi++) {
        const int row = m0 + tm * 8 + mi;
        float4 st = {acc[mi][0] + bs.x, acc[mi][1] + bs.y,
                     acc[mi][2] + bs.z, acc[mi][3] + bs.w};
        *(float4*)&out[(size_t)row * H_ + n0 + tn * 4] = st;
    }
}

// ---------------- Phase 2: MFMA scan ----------------
// 512 thr / 8 waves / waves_per_eu(2,2) — R4's proven no-spill regime.
// Per wave per step: 64 MFMAs (4 rt-chains x 16 kt). B = h broadcast to all
// 16 cols (GEMV). kt 0..11 A-frags in regs (wf[48]); kt 12..15 ds_read from
// 128KB LDS each step, 2-frag batches pipelined between reg-MFMAs.
// Tail: lane's col-group g16&3 selects its rt chain -> 4 tanh, no reduce;
// lanes g16<4 write h (global + LDS ping-pong). Raw barrier (no vmcnt drain).

#define BF(KT) (*(const uint4*)&hh[rb + (KT)*16 + hi4])
#define MFR(KT) { uint4 bf = BF(KT);                                            \
    a0 = mfma16(wf[(KT)*4+0], bf, a0); a1 = mfma16(wf[(KT)*4+1], bf, a1);       \
    a2 = mfma16(wf[(KT)*4+2], bf, a2); a3 = mfma16(wf[(KT)*4+3], bf, a3); }
#define LD2(KTS,RT) { s0 = wl[(wb+(KTS)*4+(RT))*64 + lane];                     \
                      s1 = wl[(wb+(KTS)*4+(RT)+1)*64 + lane]; }
#define MFS2(KT,AA,BB) { uint4 bf = BF(KT);                                     \
    AA = mfma16(s0, bf, AA); BB = mfma16(s1, bf, BB); }

__launch_bounds__(512)
__attribute__((amdgpu_waves_per_eu(2, 2)))
__global__ void rnn_scan(const u32* __restrict__ wregb, const u32* __restrict__ wldsg,
                         float* __restrict__ out) {
    __shared__ __align__(16) uint4 wl[8192];   // 128 KB: kt 12..15 A-frags
    __shared__ __align__(16) u32 hh[512];      // 2 x 512 fp16 h ping-pong
    const int tid = threadIdx.x;
    const int w = tid >> 6, lane = tid & 63;
    const int g16 = lane & 15, hi = lane >> 4, hi4 = hi * 4;
    const int gg = g16 & 3;
    const int orow = w * 64 + gg * 16 + hi4;   // this lane's 4 output rows
    const int hslot = w * 32 + gg * 8 + hi * 2;

    uint4 wf[48];                              // kt 0..11 (192 u32/lane)
    const uint4* wr4 = (const uint4*)wregb;
#pragma unroll
    for (int fi = 0; fi < 48; fi++) wf[fi] = wr4[(w * 48 + fi) * 64 + lane];

    const uint4* wg4 = (const uint4*)wldsg;
#pragma unroll
    for (int i = 0; i < 16; i++) wl[i * 512 + tid] = wg4[i * 512 + tid];
    hh[tid] = 0u;                              // h0 = 0 (both buffers)
    __syncthreads();

    float* outb = out + (size_t)blockIdx.x * (T_ * H_);
    int wb = w * 16;                           // LDS frag base for this wave

#pragma unroll 1
    for (int t = 0; t < T_; t++) {
        asm volatile("" : "+v"(wb));           // no LICM of invariant W ds_reads
        const int rb = (t & 1) << 8;
        float4 xp = *(const float4*)&outb[(size_t)t * H_ + orow];
        f32x4 a0 = {0.f, 0.f, 0.f, 0.f}, a1 = {0.f, 0.f, 0.f, 0.f};
        f32x4 a2 = {0.f, 0.f, 0.f, 0.f}, a3 = {0.f, 0.f, 0.f, 0.f};
        uint4 s0, s1;
        LD2(0, 0)
        MFR(0) MFR(1) MFR(2)
        MFS2(12, a0, a1) LD2(0, 2)
        MFR(3) MFR(4)
        MFS2(12, a2, a3) LD2(1, 0)
        MFR(5) MFR(6)
        MFS2(13, a0, a1) LD2(1, 2)
        MFR(7) MFR(8)
        MFS2(13, a2, a3) LD2(2, 0)
        MFR(9) MFR(10)
        MFS2(14, a0, a1) LD2(2, 2)
        MFR(11)
        MFS2(14, a2, a3) LD2(3, 0)
        MFS2(15, a0, a1) LD2(3, 2)
        MFS2(15, a2, a3)
        // tail: select this lane's rt chain (gg), finish 4 rows
        f32x4 x0v = (gg & 1) ? a1 : a0;
        f32x4 x1v = (gg & 1) ? a3 : a2;
        f32x4 z   = (gg & 2) ? x1v : x0v;
        const float t0 = tanh_f(xp.x + z[0]);
        const float t1 = tanh_f(xp.y + z[1]);
        const float t2 = tanh_f(xp.z + z[2]);
        const float t3 = tanh_f(xp.w + z[3]);
        if (g16 < 4) {
            float4 st = {t0, t1, t2, t3};
            *(float4*)&outb[(size_t)t * H_ + orow] = st;    // h_t overwrites Xp
            uint2 ph = {pkf16(t0, t1), pkf16(t2, t3)};
            *(uint2*)&hh[(rb ^ 256) + hslot] = ph;          // h -> other buffer
        }
        asm volatile("s_waitcnt lgkmcnt(0)" ::: "memory");
        __builtin_amdgcn_sched_barrier(0);
        __builtin_amdgcn_s_barrier();
        __builtin_amdgcn_sched_barrier(0);
    }
}

extern "C" void kernel_launch(void* const* d_in, const int* in_sizes, int n_in,
                              void* d_out, int out_size, void* d_ws, size_t ws_size,
                              hipStream_t stream) {
    const float* X    = (const float*)d_in[0];
    const float* Wih  = (const float*)d_in[1];
    const float* Whh  = (const float*)d_in[2];
    const float* bih  = (const float*)d_in[3];
    const float* bhh  = (const float*)d_in[4];
    float* out = (float*)d_out;
    // d_ws: wregb 384 frags (384KB) | wldsg 128 frags (128KB) = 512KB
    u32* wregb = (u32*)d_ws;
    u32* wldsg = wregb + 98304;

    prep_w<<<dim3(512), dim3(256), 0, stream>>>(Whh, wregb, wldsg);
    gemm_xp<<<dim3((65536 / BM) * (H_ / BN)), dim3(256), 0, stream>>>(X, Wih, bih, bhh, out);
    rnn_scan<<<dim3(B_), dim3(512), 0, stream>>>(wregb, wldsg, out);
}